// Round 4
// baseline (321.514 us; speedup 1.0000x reference)
//
#include <hip/hip_runtime.h>
#include <math.h>

#define B_  32
#define S_  4096
#define E_  256
#define A_  256
#define DE_ 512

typedef __attribute__((ext_vector_type(8))) short short8;
typedef __attribute__((ext_vector_type(4))) float f32x4;

__device__ inline unsigned short f2bf(float x) {
    unsigned int u = __float_as_uint(x);
    u += 0x7FFFu + ((u >> 16) & 1u);      // round-to-nearest-even
    return (unsigned short)(u >> 16);
}
__device__ inline float tanh_fast(float x) {
    x = fminf(fmaxf(x, -15.f), 15.f);
    float t = __expf(2.f * x);
    return (t - 1.f) * __builtin_amdgcn_rcpf(t + 1.f);
}

// ---- Prep: block 0..63 = pack We hi/lo bf16 (fragment order),
//            block 64..95 = proj, block 96 = zero attended region.
__global__ __launch_bounds__(256) void prep_kernel(
    const float* __restrict__ W, const float* __restrict__ dh,
    const float* __restrict__ bias, unsigned short* __restrict__ wepk,
    float* __restrict__ proj, float* __restrict__ out)
{
    __shared__ float dh_lds[E_];
    const int bk  = blockIdx.x;
    const int tid = threadIdx.x;
    if (bk < 64) {
        // unit = c*2048 + plane*1024 + kg*256 + a; 8 bf16 = We[a][c*32+kg*8..+8]
        const int idx = bk * 256 + tid;
        const int c     = idx >> 11;
        const int r     = idx & 2047;
        const int plane = r >> 10;
        const int kg    = (r >> 8) & 3;
        const int a     = r & 255;
        const float* src = W + (size_t)a * DE_ + E_ + c * 32 + kg * 8;
        unsigned int pk[4];
        #pragma unroll
        for (int j = 0; j < 4; ++j) {
            float x0 = src[2 * j], x1 = src[2 * j + 1];
            unsigned int u0 = __float_as_uint(x0) & 0xFFFF0000u;
            unsigned int u1 = __float_as_uint(x1) & 0xFFFF0000u;
            if (plane) {
                unsigned short l0 = f2bf(x0 - __uint_as_float(u0));
                unsigned short l1 = f2bf(x1 - __uint_as_float(u1));
                pk[j] = (unsigned int)l0 | ((unsigned int)l1 << 16);
            } else {
                pk[j] = (u0 >> 16) | u1;
            }
        }
        *(uint4*)&wepk[(size_t)idx * 8] = make_uint4(pk[0], pk[1], pk[2], pk[3]);
    } else if (bk < 96) {
        const int b = bk - 64;
        const int a = tid;
        dh_lds[a] = dh[b * E_ + a];
        __syncthreads();
        float acc = bias[a];
        const float* wrow = W + (size_t)a * DE_;
        #pragma unroll
        for (int d = 0; d < E_; d += 4) {
            float4 w = *(const float4*)(wrow + d);
            acc += dh_lds[d] * w.x + dh_lds[d+1] * w.y
                 + dh_lds[d+2] * w.z + dh_lds[d+3] * w.w;
        }
        proj[b * A_ + a] = acc;
    } else {
        #pragma unroll
        for (int j = tid; j < B_ * E_; j += 256) out[j] = 0.f;
    }
}

// ---- Scores v6: BARRIER-FREE K-loop. TS=64 s-rows/block, wave = 64s x 64a.
// Each lane loads its A-fragment floats eo[s0+mt*16+lr][c*32+lq*8..+8]
// DIRECTLY global->reg (8 KB chunk slice, L1/L2-hot) and converts to
// hi/lo bf16 in-register. 4x redundant convert across waves (~400 VALU
// cyc/wave/chunk) stays under the MFMA shadow (~930 cyc/wave/chunk).
// Zero __syncthreads and zero LDS traffic in the main loop: waves desync,
// MFMA pipe fed continuously by 3 resident waves/SIMD. LDS = epilogue only.
__global__ __launch_bounds__(256, 3) void scores_kernel(
    const float* __restrict__ eo, const unsigned short* __restrict__ wepk,
    const float* __restrict__ proj,
    float* __restrict__ scores, float* __restrict__ nsq)
{
    // epilogue overlay: red4 [64][66] floats @0; npart @16896; qpart @17920
    __shared__ __align__(16) unsigned char pool[18944];

    const int tid = threadIdx.x;
    const int b   = blockIdx.x & (B_ - 1);
    const int s0  = (blockIdx.x >> 5) * 64;
    const int w   = tid >> 6, l = tid & 63;   // w = a-block of this wave
    const int lq  = l >> 4,  lr = l & 15;

    // We fragment unit (16B units): c*2048 + plane*1024 + lq*256 + (w*64+nt*16+lr)
    const int wunit = lq * 256 + w * 64 + lr;
    // per-lane eo base: row s0+lr (+mt*16), cols c*32 + lq*8 .. +8
    const float* esrc = eo + (size_t)(s0 + lr) * (B_ * E_) + b * E_ + lq * 8;

    f32x4 acc[4][4];
    #pragma unroll
    for (int i = 0; i < 4; ++i)
        #pragma unroll
        for (int j = 0; j < 4; ++j)
            acc[i][j] = (f32x4){0.f, 0.f, 0.f, 0.f};
    float nacc[4] = {0.f, 0.f, 0.f, 0.f};   // k-quarter lq partial of row mt*16+lr

    for (int c = 0; c < 8; ++c) {
        // ---- issue eo raw loads for this chunk (4 rows x 32 B per lane)
        float4 r0[4], r1[4];
        #pragma unroll
        for (int mt = 0; mt < 4; ++mt) {
            const float* p = esrc + (size_t)(mt * 16) * (B_ * E_) + c * 32;
            r0[mt] = *(const float4*)(p);
            r1[mt] = *(const float4*)(p + 4);
        }
        // ---- We fragment loads (L2-hot packed buffer)
        short8 bh[4], bl[4];
        {
            const unsigned short* wsrc = wepk + (size_t)(c * 2048 + wunit) * 8;
            #pragma unroll
            for (int nt = 0; nt < 4; ++nt) {
                bh[nt] = *(const short8*)(wsrc + (size_t)(nt * 16) * 8);
                bl[nt] = *(const short8*)(wsrc + (size_t)(1024 + nt * 16) * 8);
            }
        }
        // ---- per mt: convert to hi/lo fragments, norm partial, 12 MFMA
        #pragma unroll
        for (int mt = 0; mt < 4; ++mt) {
            float xs[8] = {r0[mt].x, r0[mt].y, r0[mt].z, r0[mt].w,
                           r1[mt].x, r1[mt].y, r1[mt].z, r1[mt].w};
            nacc[mt] += xs[0]*xs[0] + xs[1]*xs[1] + xs[2]*xs[2] + xs[3]*xs[3]
                      + xs[4]*xs[4] + xs[5]*xs[5] + xs[6]*xs[6] + xs[7]*xs[7];
            union { short8 s; unsigned int u[4]; } ah, al;
            #pragma unroll
            for (int j = 0; j < 4; ++j) {
                unsigned int u0 = __float_as_uint(xs[2*j])   & 0xFFFF0000u;
                unsigned int u1 = __float_as_uint(xs[2*j+1]) & 0xFFFF0000u;
                ah.u[j] = (u0 >> 16) | u1;
                al.u[j] = (unsigned int)f2bf(xs[2*j]   - __uint_as_float(u0))
                        | ((unsigned int)f2bf(xs[2*j+1] - __uint_as_float(u1)) << 16);
            }
            #pragma unroll
            for (int nt = 0; nt < 4; ++nt) {
                acc[mt][nt] = __builtin_amdgcn_mfma_f32_16x16x32_bf16(ah.s, bh[nt], acc[mt][nt], 0, 0, 0);
                acc[mt][nt] = __builtin_amdgcn_mfma_f32_16x16x32_bf16(ah.s, bl[nt], acc[mt][nt], 0, 0, 0);
                acc[mt][nt] = __builtin_amdgcn_mfma_f32_16x16x32_bf16(al.s, bh[nt], acc[mt][nt], 0, 0, 0);
            }
        }
    }

    // ---- epilogue: tanh + reduce over a (LDS first touched here)
    float* red4  = (float*)pool;                 // [64 a-groups][66] floats
    float* npart = (float*)(pool + 16896);       // 256 floats: [mt*64 + lq*16 + lr]
    float* qpart = (float*)(pool + 17920);       // 256 floats
    float pr[4];
    #pragma unroll
    for (int nt = 0; nt < 4; ++nt) pr[nt] = proj[b * A_ + w * 64 + nt * 16 + lr];
    #pragma unroll
    for (int mt = 0; mt < 4; ++mt) {
        #pragma unroll
        for (int r = 0; r < 4; ++r) {
            float s = 0.f;
            #pragma unroll
            for (int nt = 0; nt < 4; ++nt)
                s += tanh_fast(pr[nt] + acc[mt][nt][r]);
            // C/D layout: col = lr (a-dim), row = mt*16 + lq*4 + r (s-dim)
            red4[(w * 16 + lr) * 66 + (mt * 16 + lq * 4 + r)] = s;
        }
    }
    if (w == 0) {   // all waves hold identical nacc; wave 0 publishes
        #pragma unroll
        for (int mt = 0; mt < 4; ++mt) npart[mt * 64 + l] = nacc[mt];
    }
    __syncthreads();
    {   // 256 threads: (row = tid>>2, quarter = tid&3) sums 16 of 64 a-groups
        const int row = tid >> 2, quarter = tid & 3;
        float s = 0.f;
        #pragma unroll
        for (int j = 0; j < 16; ++j) s += red4[(quarter * 16 + j) * 66 + row];
        qpart[quarter * 64 + row] = s;
    }
    __syncthreads();
    if (tid < 64) {
        scores[b * S_ + s0 + tid] = qpart[tid] + qpart[64 + tid]
                                  + qpart[128 + tid] + qpart[192 + tid];
        const int mt = tid >> 4, lr2 = tid & 15;   // row tid = mt*16 + lr2
        nsq[b * S_ + s0 + tid] = npart[mt * 64 + lr2]      + npart[mt * 64 + 16 + lr2]
                               + npart[mt * 64 + 32 + lr2] + npart[mt * 64 + 48 + lr2];
    }
}

// ---- Stats: per-b softmax stats computed ONCE (not per attend block).
// Writes attn_map, and overwrites nsq[] in-place with normalized probs
// (each element read-then-written only by its owner thread — race-free).
__global__ __launch_bounds__(256) void stats_kernel(
    const float* __restrict__ scores, float* __restrict__ nsq_pv,
    float* __restrict__ out)
{
    __shared__ float red[256];
    const int tid  = threadIdx.x;
    const int b    = blockIdx.x & (B_ - 1);
    const int part = blockIdx.x >> 5;      // 0..7: which 512-slice this block writes
    float v[16];
    float m = -1e30f;
    #pragma unroll
    for (int i = 0; i < 16; ++i) {
        v[i] = scores[b * S_ + i * 256 + tid];
        m = fmaxf(m, v[i]);
    }
    red[tid] = m;
    __syncthreads();
    for (int off = 128; off > 0; off >>= 1) {
        if (tid < off) red[tid] = fmaxf(red[tid], red[tid + off]);
        __syncthreads();
    }
    m = red[0];
    __syncthreads();
    float sum = 0.f;
    #pragma unroll
    for (int i = 0; i < 16; ++i) sum += __expf(v[i] - m);
    red[tid] = sum;
    __syncthreads();
    for (int off = 128; off > 0; off >>= 1) {
        if (tid < off) red[tid] += red[tid + off];
        __syncthreads();
    }
    const float inv = 1.f / red[0];
    #pragma unroll
    for (int j = 0; j < 2; ++j) {
        const int i = part * 2 + j;
        const int s = i * 256 + tid;
        const float pv = __expf(v[i] - m) * inv;
        out[B_ * E_ + b * S_ + s] = pv * sqrtf(nsq_pv[b * S_ + s]);
        nsq_pv[b * S_ + s] = pv;
    }
}

// ---- Attend: pure-bandwidth accumulation (no softmax recompute).
__global__ __launch_bounds__(256) void attend_kernel(
    const float* __restrict__ eo, const float* __restrict__ pv,
    float* __restrict__ out)
{
    __shared__ float4 acc_red[4][64];
    const int tid = threadIdx.x;
    const int b   = blockIdx.x & (B_ - 1);
    const int ch  = blockIdx.x / B_;
    const int le = tid & 63, sg = tid >> 6;
    const int s0 = ch * 128 + sg * 32;
    float4 a = make_float4(0.f, 0.f, 0.f, 0.f);
    #pragma unroll 8
    for (int s = 0; s < 32; ++s) {
        float p = pv[b * S_ + s0 + s];
        float4 e = *(const float4*)(eo + (size_t)(s0 + s) * (B_ * E_)
                                       + b * E_ + le * 4);
        a.x = fmaf(p, e.x, a.x);
        a.y = fmaf(p, e.y, a.y);
        a.z = fmaf(p, e.z, a.z);
        a.w = fmaf(p, e.w, a.w);
    }
    acc_red[sg][le] = a;
    __syncthreads();
    if (tid < 64) {
        float4 a0 = acc_red[0][tid], a1 = acc_red[1][tid];
        float4 a2 = acc_red[2][tid], a3 = acc_red[3][tid];
        float* dst = out + b * E_ + tid * 4;
        atomicAdd(dst + 0, a0.x + a1.x + a2.x + a3.x);
        atomicAdd(dst + 1, a0.y + a1.y + a2.y + a3.y);
        atomicAdd(dst + 2, a0.z + a1.z + a2.z + a3.z);
        atomicAdd(dst + 3, a0.w + a1.w + a2.w + a3.w);
    }
}

extern "C" void kernel_launch(void* const* d_in, const int* in_sizes, int n_in,
                              void* d_out, int out_size, void* d_ws, size_t ws_size,
                              hipStream_t stream)
{
    const float* dh   = (const float*)d_in[0];  // (1,B,D)
    const float* eo   = (const float*)d_in[1];  // (S,B,E)
    const float* W    = (const float*)d_in[2];  // (A, D+E)
    const float* bias = (const float*)d_in[3];  // (A,)
    float* out = (float*)d_out;                 // [attended 8192 | attn_map 131072]
    float* ws  = (float*)d_ws;

    float* projb  = ws;                           // 8192 floats
    float* nsqb   = ws + 8192;                    // 131072 floats (nsq, then pv in-place)
    float* scores = nsqb + S_ * B_;               // 131072 floats
    unsigned short* wepk = (unsigned short*)(scores + S_ * B_);  // 256 KB packed We

    prep_kernel   <<<97,              256, 0, stream>>>(W, dh, bias, wepk, projb, out);
    scores_kernel <<<B_ * (S_ / 64),  256, 0, stream>>>(eo, wepk, projb, scores, nsqb);
    stats_kernel  <<<B_ * 8,          256, 0, stream>>>(scores, nsqb, out);
    attend_kernel <<<B_ * (S_ / 128), 256, 0, stream>>>(eo, nsqb, out);
}

// Round 5
// 259.560 us; speedup vs baseline: 1.2387x; 1.2387x over previous
//
#include <hip/hip_runtime.h>
#include <math.h>

#define B_  32
#define S_  4096
#define E_  256
#define A_  256
#define DE_ 512

typedef __attribute__((ext_vector_type(8))) short short8;
typedef __attribute__((ext_vector_type(4))) float f32x4;

__device__ inline unsigned short f2bf(float x) {
    unsigned int u = __float_as_uint(x);
    u += 0x7FFFu + ((u >> 16) & 1u);      // round-to-nearest-even
    return (unsigned short)(u >> 16);
}
__device__ inline float tanh_fast(float x) {
    x = fminf(fmaxf(x, -15.f), 15.f);
    float t = __expf(2.f * x);
    return (t - 1.f) * __builtin_amdgcn_rcpf(t + 1.f);
}

// convert 8 floats to hi/lo bf16 planes and ds_write into buffer `buf`
// (unit eu for hi, 264+eu for lo); accumulates sum of squares into nacc.
__device__ __forceinline__ void conv_write(float4 v0, float4 v1,
                                           unsigned short* buf, int eu,
                                           float& nacc)
{
    nacc += v0.x*v0.x + v0.y*v0.y + v0.z*v0.z + v0.w*v0.w
          + v1.x*v1.x + v1.y*v1.y + v1.z*v1.z + v1.w*v1.w;
    float xs[8] = {v0.x, v0.y, v0.z, v0.w, v1.x, v1.y, v1.z, v1.w};
    unsigned int hp[4], lp[4];
    #pragma unroll
    for (int j = 0; j < 4; ++j) {
        unsigned int u0 = __float_as_uint(xs[2*j])   & 0xFFFF0000u;
        unsigned int u1 = __float_as_uint(xs[2*j+1]) & 0xFFFF0000u;
        hp[j] = (u0 >> 16) | u1;
        lp[j] = (unsigned int)f2bf(xs[2*j]   - __uint_as_float(u0))
              | ((unsigned int)f2bf(xs[2*j+1] - __uint_as_float(u1)) << 16);
    }
    *(uint4*)&buf[(size_t)eu * 8]         = make_uint4(hp[0], hp[1], hp[2], hp[3]);
    *(uint4*)&buf[(size_t)(264 + eu) * 8] = make_uint4(lp[0], lp[1], lp[2], lp[3]);
}

// ---- Prep: block 0..63 = pack We hi/lo bf16 (fragment order),
//            block 64..95 = proj, block 96 = zero attended region.
__global__ __launch_bounds__(256) void prep_kernel(
    const float* __restrict__ W, const float* __restrict__ dh,
    const float* __restrict__ bias, unsigned short* __restrict__ wepk,
    float* __restrict__ proj, float* __restrict__ out)
{
    __shared__ float dh_lds[E_];
    const int bk  = blockIdx.x;
    const int tid = threadIdx.x;
    if (bk < 64) {
        // unit = c*2048 + plane*1024 + kg*256 + a; 8 bf16 = We[a][c*32+kg*8..+8]
        const int idx = bk * 256 + tid;
        const int c     = idx >> 11;
        const int r     = idx & 2047;
        const int plane = r >> 10;
        const int kg    = (r >> 8) & 3;
        const int a     = r & 255;
        const float* src = W + (size_t)a * DE_ + E_ + c * 32 + kg * 8;
        unsigned int pk[4];
        #pragma unroll
        for (int j = 0; j < 4; ++j) {
            float x0 = src[2 * j], x1 = src[2 * j + 1];
            unsigned int u0 = __float_as_uint(x0) & 0xFFFF0000u;
            unsigned int u1 = __float_as_uint(x1) & 0xFFFF0000u;
            if (plane) {
                unsigned short l0 = f2bf(x0 - __uint_as_float(u0));
                unsigned short l1 = f2bf(x1 - __uint_as_float(u1));
                pk[j] = (unsigned int)l0 | ((unsigned int)l1 << 16);
            } else {
                pk[j] = (u0 >> 16) | u1;
            }
        }
        *(uint4*)&wepk[(size_t)idx * 8] = make_uint4(pk[0], pk[1], pk[2], pk[3]);
    } else if (bk < 96) {
        const int b = bk - 64;
        const int a = tid;
        dh_lds[a] = dh[b * E_ + a];
        __syncthreads();
        float acc = bias[a];
        const float* wrow = W + (size_t)a * DE_;
        #pragma unroll
        for (int d = 0; d < E_; d += 4) {
            float4 w = *(const float4*)(wrow + d);
            acc += dh_lds[d] * w.x + dh_lds[d+1] * w.y
                 + dh_lds[d+2] * w.z + dh_lds[d+3] * w.w;
        }
        proj[b * A_ + a] = acc;
    } else {
        #pragma unroll
        for (int j = tid; j < B_ * E_; j += 256) out[j] = 0.f;
    }
}

// ---- Scores v7: 1-barrier-per-chunk double-buffered staging.
// TS=64 s-rows/block, wave = 64s x 64a, 3 waves/SIMD.
// iter c: [ds_read A-frags c from buf[p]] [convert+write c+1 -> buf[1-p]]
//         [prefetch eo c+2] [MFMA c] [barrier].
// Hazards: writes(c+1 -> buf[1-p]) vs reads(c-1, buf[1-p]) separated by
// barrier(c-1); reads(c, buf[p]) vs writes(c+2 -> buf[p]) separated by
// barrier(c) (syncthreads drains lgkm before s_barrier). A-frags read in
// two mt-halves to keep live regs ~150 (< 170 ceiling at 3 waves/SIMD).
__global__ __launch_bounds__(256, 3) void scores_kernel(
    const float* __restrict__ eo, const unsigned short* __restrict__ wepk,
    const float* __restrict__ proj,
    float* __restrict__ scores, float* __restrict__ nsq)
{
    // main: two eo buffers of 528 units (16 B each): [0,8448) and [8448,16896)
    // epilogue overlay: red4 [64][66] floats @0; npart @16896; qpart @17920
    __shared__ __align__(16) unsigned char pool[18944];
    unsigned short* eo_hl = (unsigned short*)pool;

    const int tid = threadIdx.x;
    const int b   = blockIdx.x & (B_ - 1);
    const int s0  = (blockIdx.x >> 5) * 64;
    const int w   = tid >> 6, l = tid & 63;   // w = a-block of this wave
    const int lq  = l >> 4,  lr = l & 15;

    // eo staging map: 4 lanes per row, lane covers one kg (8 floats, 32 B)
    const int erow = tid >> 2;          // 0..63
    const int ekg  = tid & 3;
    const float* ebase = eo + (size_t)(s0 + erow) * (B_ * E_) + b * E_ + ekg * 8;
    const int eu = ekg * 66 + erow;     // write unit within a buffer

    // We fragment unit (16B units): c*2048 + plane*1024 + lq*256 + (w*64+nt*16+lr)
    const int wunit = lq * 256 + w * 64 + lr;

    f32x4 acc[4][4];
    #pragma unroll
    for (int i = 0; i < 4; ++i)
        #pragma unroll
        for (int j = 0; j < 4; ++j)
            acc[i][j] = (f32x4){0.f, 0.f, 0.f, 0.f};
    float nacc = 0.f;

    // proj values for the epilogue (tiny, L2-hot; hoisted off the critical end)
    float pr[4];
    #pragma unroll
    for (int nt = 0; nt < 4; ++nt) pr[nt] = proj[b * A_ + w * 64 + nt * 16 + lr];

    // ---- prologue: stage chunk 0 into buf0, load chunk-1 regs
    {
        float4 v0 = *(const float4*)(ebase);
        float4 v1 = *(const float4*)(ebase + 4);
        conv_write(v0, v1, eo_hl, eu, nacc);
    }
    float4 va0 = *(const float4*)(ebase + 32);
    float4 va1 = *(const float4*)(ebase + 36);
    __syncthreads();

    for (int c = 0; c < 8; ++c) {
        const int p = c & 1;
        unsigned short* rb = eo_hl + (size_t)p * 528 * 8;        // read buf
        unsigned short* wb = eo_hl + (size_t)(1 - p) * 528 * 8;  // write buf

        // ---- We fragment loads (global, L2-hot; in flight through convert)
        short8 bh[4], bl[4];
        {
            const unsigned short* wsrc = wepk + (size_t)(c * 2048 + wunit) * 8;
            #pragma unroll
            for (int nt = 0; nt < 4; ++nt) {
                bh[nt] = *(const short8*)(wsrc + (size_t)(nt * 16) * 8);
                bl[nt] = *(const short8*)(wsrc + (size_t)(1024 + nt * 16) * 8);
            }
        }
        // ---- A-frag reads, first half (mt 0,1)
        short8 ah[2], al[2];
        #pragma unroll
        for (int mt = 0; mt < 2; ++mt) {
            const int au = lq * 66 + mt * 16 + lr;
            ah[mt] = *(const short8*)&rb[(size_t)au * 8];
            al[mt] = *(const short8*)&rb[(size_t)(264 + au) * 8];
        }
        // ---- convert + write chunk c+1 into wb (hides the ds_read latency)
        if (c < 7) conv_write(va0, va1, wb, eu, nacc);
        // ---- prefetch eo chunk c+2
        if (c < 6) {
            va0 = *(const float4*)(ebase + (c + 2) * 32);
            va1 = *(const float4*)(ebase + (c + 2) * 32 + 4);
        }
        // ---- MFMA first half
        #pragma unroll
        for (int mt = 0; mt < 2; ++mt) {
            #pragma unroll
            for (int nt = 0; nt < 4; ++nt) {
                acc[mt][nt] = __builtin_amdgcn_mfma_f32_16x16x32_bf16(ah[mt], bh[nt], acc[mt][nt], 0, 0, 0);
                acc[mt][nt] = __builtin_amdgcn_mfma_f32_16x16x32_bf16(ah[mt], bl[nt], acc[mt][nt], 0, 0, 0);
                acc[mt][nt] = __builtin_amdgcn_mfma_f32_16x16x32_bf16(al[mt], bh[nt], acc[mt][nt], 0, 0, 0);
            }
        }
        // ---- A-frag reads + MFMA, second half (mt 2,3)
        #pragma unroll
        for (int mt = 2; mt < 4; ++mt) {
            const int au = lq * 66 + mt * 16 + lr;
            short8 ah2 = *(const short8*)&rb[(size_t)au * 8];
            short8 al2 = *(const short8*)&rb[(size_t)(264 + au) * 8];
            #pragma unroll
            for (int nt = 0; nt < 4; ++nt) {
                acc[mt][nt] = __builtin_amdgcn_mfma_f32_16x16x32_bf16(ah2, bh[nt], acc[mt][nt], 0, 0, 0);
                acc[mt][nt] = __builtin_amdgcn_mfma_f32_16x16x32_bf16(ah2, bl[nt], acc[mt][nt], 0, 0, 0);
                acc[mt][nt] = __builtin_amdgcn_mfma_f32_16x16x32_bf16(al2, bh[nt], acc[mt][nt], 0, 0, 0);
            }
        }
        if (c < 7) __syncthreads();
    }
    __syncthreads();   // all fragment reads done before LDS overlay

    // ---- epilogue: tanh + reduce over a
    float* red4  = (float*)pool;                 // [64 a-groups][66] floats
    float* npart = (float*)(pool + 16896);       // 256 floats
    float* qpart = (float*)(pool + 17920);       // 256 floats
    #pragma unroll
    for (int mt = 0; mt < 4; ++mt) {
        #pragma unroll
        for (int r = 0; r < 4; ++r) {
            float s = 0.f;
            #pragma unroll
            for (int nt = 0; nt < 4; ++nt)
                s += tanh_fast(pr[nt] + acc[mt][nt][r]);
            // C/D layout: col = lr (a-dim), row = mt*16 + lq*4 + r (s-dim)
            red4[(w * 16 + lr) * 66 + (mt * 16 + lq * 4 + r)] = s;
        }
    }
    npart[tid] = nacc;    // partial (1/4 of E) of row tid>>2
    __syncthreads();
    {   // 256 threads: (row = tid>>2, quarter = tid&3) sums 16 of 64 a-groups
        const int row = tid >> 2, quarter = tid & 3;
        float s = 0.f;
        #pragma unroll
        for (int j = 0; j < 16; ++j) s += red4[(quarter * 16 + j) * 66 + row];
        qpart[quarter * 64 + row] = s;
    }
    __syncthreads();
    if (tid < 64) {
        scores[b * S_ + s0 + tid] = qpart[tid] + qpart[64 + tid]
                                  + qpart[128 + tid] + qpart[192 + tid];
        nsq[b * S_ + s0 + tid] = npart[4 * tid] + npart[4 * tid + 1]
                               + npart[4 * tid + 2] + npart[4 * tid + 3];
    }
}

// ---- Stats: per-b softmax stats computed ONCE (not per attend block).
// Writes attn_map, and overwrites nsq[] in-place with normalized probs
// (each element read-then-written only by its owner thread — race-free).
__global__ __launch_bounds__(256) void stats_kernel(
    const float* __restrict__ scores, float* __restrict__ nsq_pv,
    float* __restrict__ out)
{
    __shared__ float red[256];
    const int tid  = threadIdx.x;
    const int b    = blockIdx.x & (B_ - 1);
    const int part = blockIdx.x >> 5;      // 0..7: which 512-slice this block writes
    float v[16];
    float m = -1e30f;
    #pragma unroll
    for (int i = 0; i < 16; ++i) {
        v[i] = scores[b * S_ + i * 256 + tid];
        m = fmaxf(m, v[i]);
    }
    red[tid] = m;
    __syncthreads();
    for (int off = 128; off > 0; off >>= 1) {
        if (tid < off) red[tid] = fmaxf(red[tid], red[tid + off]);
        __syncthreads();
    }
    m = red[0];
    __syncthreads();
    float sum = 0.f;
    #pragma unroll
    for (int i = 0; i < 16; ++i) sum += __expf(v[i] - m);
    red[tid] = sum;
    __syncthreads();
    for (int off = 128; off > 0; off >>= 1) {
        if (tid < off) red[tid] += red[tid + off];
        __syncthreads();
    }
    const float inv = 1.f / red[0];
    #pragma unroll
    for (int j = 0; j < 2; ++j) {
        const int i = part * 2 + j;
        const int s = i * 256 + tid;
        const float pv = __expf(v[i] - m) * inv;
        out[B_ * E_ + b * S_ + s] = pv * sqrtf(nsq_pv[b * S_ + s]);
        nsq_pv[b * S_ + s] = pv;
    }
}

// ---- Attend: pure-bandwidth accumulation (no softmax recompute).
__global__ __launch_bounds__(256) void attend_kernel(
    const float* __restrict__ eo, const float* __restrict__ pv,
    float* __restrict__ out)
{
    __shared__ float4 acc_red[4][64];
    const int tid = threadIdx.x;
    const int b   = blockIdx.x & (B_ - 1);
    const int ch  = blockIdx.x / B_;
    const int le = tid & 63, sg = tid >> 6;
    const int s0 = ch * 128 + sg * 32;
    float4 a = make_float4(0.f, 0.f, 0.f, 0.f);
    #pragma unroll 8
    for (int s = 0; s < 32; ++s) {
        float p = pv[b * S_ + s0 + s];
        float4 e = *(const float4*)(eo + (size_t)(s0 + s) * (B_ * E_)
                                       + b * E_ + le * 4);
        a.x = fmaf(p, e.x, a.x);
        a.y = fmaf(p, e.y, a.y);
        a.z = fmaf(p, e.z, a.z);
        a.w = fmaf(p, e.w, a.w);
    }
    acc_red[sg][le] = a;
    __syncthreads();
    if (tid < 64) {
        float4 a0 = acc_red[0][tid], a1 = acc_red[1][tid];
        float4 a2 = acc_red[2][tid], a3 = acc_red[3][tid];
        float* dst = out + b * E_ + tid * 4;
        atomicAdd(dst + 0, a0.x + a1.x + a2.x + a3.x);
        atomicAdd(dst + 1, a0.y + a1.y + a2.y + a3.y);
        atomicAdd(dst + 2, a0.z + a1.z + a2.z + a3.z);
        atomicAdd(dst + 3, a0.w + a1.w + a2.w + a3.w);
    }
}

extern "C" void kernel_launch(void* const* d_in, const int* in_sizes, int n_in,
                              void* d_out, int out_size, void* d_ws, size_t ws_size,
                              hipStream_t stream)
{
    const float* dh   = (const float*)d_in[0];  // (1,B,D)
    const float* eo   = (const float*)d_in[1];  // (S,B,E)
    const float* W    = (const float*)d_in[2];  // (A, D+E)
    const float* bias = (const float*)d_in[3];  // (A,)
    float* out = (float*)d_out;                 // [attended 8192 | attn_map 131072]
    float* ws  = (float*)d_ws;

    float* projb  = ws;                           // 8192 floats
    float* nsqb   = ws + 8192;                    // 131072 floats (nsq, then pv in-place)
    float* scores = nsqb + S_ * B_;               // 131072 floats
    unsigned short* wepk = (unsigned short*)(scores + S_ * B_);  // 256 KB packed We

    prep_kernel   <<<97,              256, 0, stream>>>(W, dh, bias, wepk, projb, out);
    scores_kernel <<<B_ * (S_ / 64),  256, 0, stream>>>(eo, wepk, projb, scores, nsqb);
    stats_kernel  <<<B_ * 8,          256, 0, stream>>>(scores, nsqb, out);
    attend_kernel <<<B_ * (S_ / 128), 256, 0, stream>>>(eo, nsqb, out);
}

// Round 6
// 254.330 us; speedup vs baseline: 1.2642x; 1.0206x over previous
//
#include <hip/hip_runtime.h>
#include <math.h>

#define B_  32
#define S_  4096
#define E_  256
#define A_  256
#define DE_ 512

typedef __attribute__((ext_vector_type(8))) short short8;
typedef __attribute__((ext_vector_type(4))) float f32x4;

__device__ inline unsigned short f2bf(float x) {
    unsigned int u = __float_as_uint(x);
    u += 0x7FFFu + ((u >> 16) & 1u);      // round-to-nearest-even
    return (unsigned short)(u >> 16);
}
__device__ inline float tanh_fast(float x) {
    x = fminf(fmaxf(x, -15.f), 15.f);
    float t = __expf(2.f * x);
    return (t - 1.f) * __builtin_amdgcn_rcpf(t + 1.f);
}

// convert 8 floats to hi/lo bf16 planes and ds_write into buffer `buf`
// (unit eu for hi, 264+eu for lo); accumulates sum of squares into nacc.
__device__ __forceinline__ void conv_write(float4 v0, float4 v1,
                                           unsigned short* buf, int eu,
                                           float& nacc)
{
    nacc += v0.x*v0.x + v0.y*v0.y + v0.z*v0.z + v0.w*v0.w
          + v1.x*v1.x + v1.y*v1.y + v1.z*v1.z + v1.w*v1.w;
    float xs[8] = {v0.x, v0.y, v0.z, v0.w, v1.x, v1.y, v1.z, v1.w};
    unsigned int hp[4], lp[4];
    #pragma unroll
    for (int j = 0; j < 4; ++j) {
        unsigned int u0 = __float_as_uint(xs[2*j])   & 0xFFFF0000u;
        unsigned int u1 = __float_as_uint(xs[2*j+1]) & 0xFFFF0000u;
        hp[j] = (u0 >> 16) | u1;
        lp[j] = (unsigned int)f2bf(xs[2*j]   - __uint_as_float(u0))
              | ((unsigned int)f2bf(xs[2*j+1] - __uint_as_float(u1)) << 16);
    }
    *(uint4*)&buf[(size_t)eu * 8]         = make_uint4(hp[0], hp[1], hp[2], hp[3]);
    *(uint4*)&buf[(size_t)(264 + eu) * 8] = make_uint4(lp[0], lp[1], lp[2], lp[3]);
}

// ---- Prep: block 0..63 = pack We hi/lo bf16 (fragment order),
//            block 64..95 = proj, block 96 = zero attended region.
__global__ __launch_bounds__(256) void prep_kernel(
    const float* __restrict__ W, const float* __restrict__ dh,
    const float* __restrict__ bias, unsigned short* __restrict__ wepk,
    float* __restrict__ proj, float* __restrict__ out)
{
    __shared__ float dh_lds[E_];
    const int bk  = blockIdx.x;
    const int tid = threadIdx.x;
    if (bk < 64) {
        // unit = c*2048 + plane*1024 + kg*256 + a; 8 bf16 = We[a][c*32+kg*8..+8]
        const int idx = bk * 256 + tid;
        const int c     = idx >> 11;
        const int r     = idx & 2047;
        const int plane = r >> 10;
        const int kg    = (r >> 8) & 3;
        const int a     = r & 255;
        const float* src = W + (size_t)a * DE_ + E_ + c * 32 + kg * 8;
        unsigned int pk[4];
        #pragma unroll
        for (int j = 0; j < 4; ++j) {
            float x0 = src[2 * j], x1 = src[2 * j + 1];
            unsigned int u0 = __float_as_uint(x0) & 0xFFFF0000u;
            unsigned int u1 = __float_as_uint(x1) & 0xFFFF0000u;
            if (plane) {
                unsigned short l0 = f2bf(x0 - __uint_as_float(u0));
                unsigned short l1 = f2bf(x1 - __uint_as_float(u1));
                pk[j] = (unsigned int)l0 | ((unsigned int)l1 << 16);
            } else {
                pk[j] = (u0 >> 16) | u1;
            }
        }
        *(uint4*)&wepk[(size_t)idx * 8] = make_uint4(pk[0], pk[1], pk[2], pk[3]);
    } else if (bk < 96) {
        const int b = bk - 64;
        const int a = tid;
        dh_lds[a] = dh[b * E_ + a];
        __syncthreads();
        float acc = bias[a];
        const float* wrow = W + (size_t)a * DE_;
        #pragma unroll
        for (int d = 0; d < E_; d += 4) {
            float4 w = *(const float4*)(wrow + d);
            acc += dh_lds[d] * w.x + dh_lds[d+1] * w.y
                 + dh_lds[d+2] * w.z + dh_lds[d+3] * w.w;
        }
        proj[b * A_ + a] = acc;
    } else {
        #pragma unroll
        for (int j = tid; j < B_ * E_; j += 256) out[j] = 0.f;
    }
}

// ---- Scores v8: 2 chunks per barrier period, raw s_barrier with
// lgkmcnt(0) ONLY (vmcnt never drained in the loop -> eo prefetches ride
// across barriers, per T4). 4 LDS buffers rotate (chunk c -> buf[c&3]);
// within every period the write-set {(2p+2)&3,(2p+3)&3} is disjoint from
// the read-set {2p&3,(2p+1)&3}, and cross-period hazards are separated by
// the lgkm-drained barrier. s_setprio(1) wraps the MFMA clusters (T5).
// TS=64 s-rows/block, wave = 64s x 64a, 3 waves/SIMD.
__global__ __launch_bounds__(256, 3) void scores_kernel(
    const float* __restrict__ eo, const unsigned short* __restrict__ wepk,
    const float* __restrict__ proj,
    float* __restrict__ scores, float* __restrict__ nsq)
{
    // main: 4 eo buffers of 528 units (16 B each) = 33792 B
    // epilogue overlay: red4 [64][66] floats @0; npart @16896; qpart @17920
    __shared__ __align__(16) unsigned char pool[33792];
    unsigned short* eo_hl = (unsigned short*)pool;

    const int tid = threadIdx.x;
    const int b   = blockIdx.x & (B_ - 1);
    const int s0  = (blockIdx.x >> 5) * 64;
    const int w   = tid >> 6, l = tid & 63;   // w = a-block of this wave
    const int lq  = l >> 4,  lr = l & 15;

    // eo staging map: 4 lanes per row, lane covers one kg (8 floats, 32 B)
    const int erow = tid >> 2;          // 0..63
    const int ekg  = tid & 3;
    const float* ebase = eo + (size_t)(s0 + erow) * (B_ * E_) + b * E_ + ekg * 8;
    const int eu = ekg * 66 + erow;     // write unit within a buffer

    // We fragment unit (16B units): c*2048 + plane*1024 + lq*256 + (w*64+nt*16+lr)
    const int wunit = lq * 256 + w * 64 + lr;

    f32x4 acc[4][4];
    #pragma unroll
    for (int i = 0; i < 4; ++i)
        #pragma unroll
        for (int j = 0; j < 4; ++j)
            acc[i][j] = (f32x4){0.f, 0.f, 0.f, 0.f};
    float nacc = 0.f;

    // proj values for the epilogue (tiny, L2-hot; hoisted off the critical end)
    float pr[4];
    #pragma unroll
    for (int nt = 0; nt < 4; ++nt) pr[nt] = proj[b * A_ + w * 64 + nt * 16 + lr];

    // ---- prologue: stage chunks 0,1 into bufs 0,1; prefetch regs for 2,3
    {
        float4 v0 = *(const float4*)(ebase);
        float4 v1 = *(const float4*)(ebase + 4);
        conv_write(v0, v1, eo_hl, eu, nacc);
        float4 v2 = *(const float4*)(ebase + 32);
        float4 v3 = *(const float4*)(ebase + 36);
        conv_write(v2, v3, eo_hl + (size_t)528 * 8, eu, nacc);
    }
    float4 vaA0 = *(const float4*)(ebase + 64);
    float4 vaA1 = *(const float4*)(ebase + 68);
    float4 vaB0 = *(const float4*)(ebase + 96);
    float4 vaB1 = *(const float4*)(ebase + 100);
    asm volatile("s_waitcnt lgkmcnt(0)\ns_barrier" ::: "memory");

    for (int p = 0; p < 4; ++p) {
        const int c0 = 2 * p, c1 = 2 * p + 1;
        unsigned short* rb0 = eo_hl + (size_t)(c0 & 3) * 528 * 8;
        unsigned short* rb1 = eo_hl + (size_t)(c1 & 3) * 528 * 8;
        unsigned short* wb0 = eo_hl + (size_t)((c0 + 2) & 3) * 528 * 8;
        unsigned short* wb1 = eo_hl + (size_t)((c1 + 2) & 3) * 528 * 8;

        // ================= chunk c0 =================
        {
            short8 bh[4], bl[4];
            const unsigned short* wsrc = wepk + (size_t)(c0 * 2048 + wunit) * 8;
            #pragma unroll
            for (int nt = 0; nt < 4; ++nt) {
                bh[nt] = *(const short8*)(wsrc + (size_t)(nt * 16) * 8);
                bl[nt] = *(const short8*)(wsrc + (size_t)(1024 + nt * 16) * 8);
            }
            short8 ah[2], al[2];
            #pragma unroll
            for (int mt = 0; mt < 2; ++mt) {
                const int au = lq * 66 + mt * 16 + lr;
                ah[mt] = *(const short8*)&rb0[(size_t)au * 8];
                al[mt] = *(const short8*)&rb0[(size_t)(264 + au) * 8];
            }
            // stage chunk c0+2 while the ds_reads are in flight
            if (p < 3) conv_write(vaA0, vaA1, wb0, eu, nacc);
            __builtin_amdgcn_s_setprio(1);
            #pragma unroll
            for (int mt = 0; mt < 2; ++mt) {
                #pragma unroll
                for (int nt = 0; nt < 4; ++nt) {
                    acc[mt][nt] = __builtin_amdgcn_mfma_f32_16x16x32_bf16(ah[mt], bh[nt], acc[mt][nt], 0, 0, 0);
                    acc[mt][nt] = __builtin_amdgcn_mfma_f32_16x16x32_bf16(ah[mt], bl[nt], acc[mt][nt], 0, 0, 0);
                    acc[mt][nt] = __builtin_amdgcn_mfma_f32_16x16x32_bf16(al[mt], bh[nt], acc[mt][nt], 0, 0, 0);
                }
            }
            __builtin_amdgcn_s_setprio(0);
            #pragma unroll
            for (int mt = 2; mt < 4; ++mt) {
                const int au = lq * 66 + mt * 16 + lr;
                short8 ah2 = *(const short8*)&rb0[(size_t)au * 8];
                short8 al2 = *(const short8*)&rb0[(size_t)(264 + au) * 8];
                __builtin_amdgcn_s_setprio(1);
                #pragma unroll
                for (int nt = 0; nt < 4; ++nt) {
                    acc[mt][nt] = __builtin_amdgcn_mfma_f32_16x16x32_bf16(ah2, bh[nt], acc[mt][nt], 0, 0, 0);
                    acc[mt][nt] = __builtin_amdgcn_mfma_f32_16x16x32_bf16(ah2, bl[nt], acc[mt][nt], 0, 0, 0);
                    acc[mt][nt] = __builtin_amdgcn_mfma_f32_16x16x32_bf16(al2, bh[nt], acc[mt][nt], 0, 0, 0);
                }
                __builtin_amdgcn_s_setprio(0);
            }
        }
        // ================= chunk c1 =================
        {
            short8 bh[4], bl[4];
            const unsigned short* wsrc = wepk + (size_t)(c1 * 2048 + wunit) * 8;
            #pragma unroll
            for (int nt = 0; nt < 4; ++nt) {
                bh[nt] = *(const short8*)(wsrc + (size_t)(nt * 16) * 8);
                bl[nt] = *(const short8*)(wsrc + (size_t)(1024 + nt * 16) * 8);
            }
            short8 ah[2], al[2];
            #pragma unroll
            for (int mt = 0; mt < 2; ++mt) {
                const int au = lq * 66 + mt * 16 + lr;
                ah[mt] = *(const short8*)&rb1[(size_t)au * 8];
                al[mt] = *(const short8*)&rb1[(size_t)(264 + au) * 8];
            }
            if (p < 3) conv_write(vaB0, vaB1, wb1, eu, nacc);
            __builtin_amdgcn_s_setprio(1);
            #pragma unroll
            for (int mt = 0; mt < 2; ++mt) {
                #pragma unroll
                for (int nt = 0; nt < 4; ++nt) {
                    acc[mt][nt] = __builtin_amdgcn_mfma_f32_16x16x32_bf16(ah[mt], bh[nt], acc[mt][nt], 0, 0, 0);
                    acc[mt][nt] = __builtin_amdgcn_mfma_f32_16x16x32_bf16(ah[mt], bl[nt], acc[mt][nt], 0, 0, 0);
                    acc[mt][nt] = __builtin_amdgcn_mfma_f32_16x16x32_bf16(al[mt], bh[nt], acc[mt][nt], 0, 0, 0);
                }
            }
            __builtin_amdgcn_s_setprio(0);
            #pragma unroll
            for (int mt = 2; mt < 4; ++mt) {
                const int au = lq * 66 + mt * 16 + lr;
                short8 ah2 = *(const short8*)&rb1[(size_t)au * 8];
                short8 al2 = *(const short8*)&rb1[(size_t)(264 + au) * 8];
                __builtin_amdgcn_s_setprio(1);
                #pragma unroll
                for (int nt = 0; nt < 4; ++nt) {
                    acc[mt][nt] = __builtin_amdgcn_mfma_f32_16x16x32_bf16(ah2, bh[nt], acc[mt][nt], 0, 0, 0);
                    acc[mt][nt] = __builtin_amdgcn_mfma_f32_16x16x32_bf16(ah2, bl[nt], acc[mt][nt], 0, 0, 0);
                    acc[mt][nt] = __builtin_amdgcn_mfma_f32_16x16x32_bf16(al2, bh[nt], acc[mt][nt], 0, 0, 0);
                }
                __builtin_amdgcn_s_setprio(0);
            }
        }
        // ---- prefetch eo regs for chunks 2p+4, 2p+5 (ride across barrier)
        if (p < 2) {
            vaA0 = *(const float4*)(ebase + (2 * p + 4) * 32);
            vaA1 = *(const float4*)(ebase + (2 * p + 4) * 32 + 4);
            vaB0 = *(const float4*)(ebase + (2 * p + 5) * 32);
            vaB1 = *(const float4*)(ebase + (2 * p + 5) * 32 + 4);
        }
        // barrier: drain LDS ops only; vmcnt stays outstanding
        asm volatile("s_waitcnt lgkmcnt(0)\ns_barrier" ::: "memory");
    }
    __syncthreads();   // full drain before LDS overlay

    // ---- epilogue: tanh + reduce over a
    float* red4  = (float*)pool;                 // [64 a-groups][66] floats
    float* npart = (float*)(pool + 16896);       // 256 floats
    float* qpart = (float*)(pool + 17920);       // 256 floats
    #pragma unroll
    for (int mt = 0; mt < 4; ++mt) {
        #pragma unroll
        for (int r = 0; r < 4; ++r) {
            float s = 0.f;
            #pragma unroll
            for (int nt = 0; nt < 4; ++nt)
                s += tanh_fast(pr[nt] + acc[mt][nt][r]);
            // C/D layout: col = lr (a-dim), row = mt*16 + lq*4 + r (s-dim)
            red4[(w * 16 + lr) * 66 + (mt * 16 + lq * 4 + r)] = s;
        }
    }
    npart[tid] = nacc;    // partial (1/4 of E) of row tid>>2
    __syncthreads();
    {   // 256 threads: (row = tid>>2, quarter = tid&3) sums 16 of 64 a-groups
        const int row = tid >> 2, quarter = tid & 3;
        float s = 0.f;
        #pragma unroll
        for (int j = 0; j < 16; ++j) s += red4[(quarter * 16 + j) * 66 + row];
        qpart[quarter * 64 + row] = s;
    }
    __syncthreads();
    if (tid < 64) {
        scores[b * S_ + s0 + tid] = qpart[tid] + qpart[64 + tid]
                                  + qpart[128 + tid] + qpart[192 + tid];
        nsq[b * S_ + s0 + tid] = npart[4 * tid] + npart[4 * tid + 1]
                               + npart[4 * tid + 2] + npart[4 * tid + 3];
    }
}

// ---- Stats: per-b softmax stats computed ONCE (not per attend block).
// Writes attn_map, and overwrites nsq[] in-place with normalized probs
// (each element read-then-written only by its owner thread — race-free).
__global__ __launch_bounds__(256) void stats_kernel(
    const float* __restrict__ scores, float* __restrict__ nsq_pv,
    float* __restrict__ out)
{
    __shared__ float red[256];
    const int tid  = threadIdx.x;
    const int b    = blockIdx.x & (B_ - 1);
    const int part = blockIdx.x >> 5;      // 0..7: which 512-slice this block writes
    float v[16];
    float m = -1e30f;
    #pragma unroll
    for (int i = 0; i < 16; ++i) {
        v[i] = scores[b * S_ + i * 256 + tid];
        m = fmaxf(m, v[i]);
    }
    red[tid] = m;
    __syncthreads();
    for (int off = 128; off > 0; off >>= 1) {
        if (tid < off) red[tid] = fmaxf(red[tid], red[tid + off]);
        __syncthreads();
    }
    m = red[0];
    __syncthreads();
    float sum = 0.f;
    #pragma unroll
    for (int i = 0; i < 16; ++i) sum += __expf(v[i] - m);
    red[tid] = sum;
    __syncthreads();
    for (int off = 128; off > 0; off >>= 1) {
        if (tid < off) red[tid] += red[tid + off];
        __syncthreads();
    }
    const float inv = 1.f / red[0];
    #pragma unroll
    for (int j = 0; j < 2; ++j) {
        const int i = part * 2 + j;
        const int s = i * 256 + tid;
        const float pv = __expf(v[i] - m) * inv;
        out[B_ * E_ + b * S_ + s] = pv * sqrtf(nsq_pv[b * S_ + s]);
        nsq_pv[b * S_ + s] = pv;
    }
}

// ---- Attend: pure-bandwidth accumulation (no softmax recompute).
__global__ __launch_bounds__(256) void attend_kernel(
    const float* __restrict__ eo, const float* __restrict__ pv,
    float* __restrict__ out)
{
    __shared__ float4 acc_red[4][64];
    const int tid = threadIdx.x;
    const int b   = blockIdx.x & (B_ - 1);
    const int ch  = blockIdx.x / B_;
    const int le = tid & 63, sg = tid >> 6;
    const int s0 = ch * 128 + sg * 32;
    float4 a = make_float4(0.f, 0.f, 0.f, 0.f);
    #pragma unroll 8
    for (int s = 0; s < 32; ++s) {
        float p = pv[b * S_ + s0 + s];
        float4 e = *(const float4*)(eo + (size_t)(s0 + s) * (B_ * E_)
                                       + b * E_ + le * 4);
        a.x = fmaf(p, e.x, a.x);
        a.y = fmaf(p, e.y, a.y);
        a.z = fmaf(p, e.z, a.z);
        a.w = fmaf(p, e.w, a.w);
    }
    acc_red[sg][le] = a;
    __syncthreads();
    if (tid < 64) {
        float4 a0 = acc_red[0][tid], a1 = acc_red[1][tid];
        float4 a2 = acc_red[2][tid], a3 = acc_red[3][tid];
        float* dst = out + b * E_ + tid * 4;
        atomicAdd(dst + 0, a0.x + a1.x + a2.x + a3.x);
        atomicAdd(dst + 1, a0.y + a1.y + a2.y + a3.y);
        atomicAdd(dst + 2, a0.z + a1.z + a2.z + a3.z);
        atomicAdd(dst + 3, a0.w + a1.w + a2.w + a3.w);
    }
}

extern "C" void kernel_launch(void* const* d_in, const int* in_sizes, int n_in,
                              void* d_out, int out_size, void* d_ws, size_t ws_size,
                              hipStream_t stream)
{
    const float* dh   = (const float*)d_in[0];  // (1,B,D)
    const float* eo   = (const float*)d_in[1];  // (S,B,E)
    const float* W    = (const float*)d_in[2];  // (A, D+E)
    const float* bias = (const float*)d_in[3];  // (A,)
    float* out = (float*)d_out;                 // [attended 8192 | attn_map 131072]
    float* ws  = (float*)d_ws;

    float* projb  = ws;                           // 8192 floats
    float* nsqb   = ws + 8192;                    // 131072 floats (nsq, then pv in-place)
    float* scores = nsqb + S_ * B_;               // 131072 floats
    unsigned short* wepk = (unsigned short*)(scores + S_ * B_);  // 256 KB packed We

    prep_kernel   <<<97,              256, 0, stream>>>(W, dh, bias, wepk, projb, out);
    scores_kernel <<<B_ * (S_ / 64),  256, 0, stream>>>(eo, wepk, projb, scores, nsqb);
    stats_kernel  <<<B_ * 8,          256, 0, stream>>>(scores, nsqb, out);
    attend_kernel <<<B_ * (S_ / 128), 256, 0, stream>>>(eo, nsqb, out);
}